// Round 1
// baseline (1107.184 us; speedup 1.0000x reference)
//
#include <hip/hip_runtime.h>
#include <hip/hip_bf16.h>

// ---------------------------------------------------------------------------
// Transformer block (LN1 -> QKV -> MHA -> proj+res -> LN2 -> MLP+res)
// B=2, L=2048, D=768, H=12, hd=64, MLP=3072. fp32 in/out, bf16 MFMA inside.
// Round 0: correctness-first. GEMMs = 64x64-tile bf16 MFMA w/ LDS staging.
// Attention = vector fp32 flash (MFMA attention next round).
// ---------------------------------------------------------------------------

#define DIM     768
#define SEQ     2048
#define BATCH   2
#define NHEAD   12
#define HD      64
#define MLPH    3072
#define ROWS    (BATCH * SEQ)      // 4096
#define QKVW    (3 * DIM)          // 2304
#define ATT_SCALE 0.125f           // 64^-0.5

typedef __attribute__((ext_vector_type(8))) short          bf16x8;
typedef __attribute__((ext_vector_type(8))) unsigned short ushort8;
typedef __attribute__((ext_vector_type(4))) float          f32x4;

__device__ __forceinline__ float bf2f(unsigned short u) {
    union { unsigned int i; float f; } c; c.i = ((unsigned int)u) << 16; return c.f;
}
__device__ __forceinline__ unsigned short f2bf(float f) {
    union { float f; unsigned int i; } c; c.f = f;
    unsigned int i = c.i;
    return (unsigned short)((i + 0x7FFFu + ((i >> 16) & 1u)) >> 16);
}

// --------------------------- weight transpose+cast -------------------------
// in [K][N] fp32 -> out [N][K] bf16 bits. Dims multiples of 32.
__global__ __launch_bounds__(256) void transpose_cast(
    const float* __restrict__ in, unsigned short* __restrict__ out, int K, int N)
{
    __shared__ float tile[32][33];
    const int n0 = blockIdx.x * 32, k0 = blockIdx.y * 32;
    const int tx = threadIdx.x, ty = threadIdx.y;   // block (32,8)
#pragma unroll
    for (int i = 0; i < 4; ++i)
        tile[ty + i * 8][tx] = in[(size_t)(k0 + ty + i * 8) * N + n0 + tx];
    __syncthreads();
#pragma unroll
    for (int i = 0; i < 4; ++i)
        out[(size_t)(n0 + ty + i * 8) * K + k0 + tx] = f2bf(tile[tx][ty + i * 8]);
}

// --------------------------------- layernorm -------------------------------
// one row (768 fp32) per block of 256 threads -> bf16 out
__global__ __launch_bounds__(256) void ln_fwd(
    const float* __restrict__ x, const float* __restrict__ w,
    unsigned short* __restrict__ out)
{
    const int row = blockIdx.x;
    const int tid = threadIdx.x;
    const size_t base = (size_t)row * DIM;
    float v0 = x[base + tid], v1 = x[base + tid + 256], v2 = x[base + tid + 512];
    float sum = v0 + v1 + v2;
    float sq  = v0 * v0 + v1 * v1 + v2 * v2;
#pragma unroll
    for (int off = 1; off < 64; off <<= 1) {
        sum += __shfl_xor(sum, off);
        sq  += __shfl_xor(sq,  off);
    }
    __shared__ float rs[4], rq[4];
    const int wid = tid >> 6, lane = tid & 63;
    if (lane == 0) { rs[wid] = sum; rq[wid] = sq; }
    __syncthreads();
    sum = rs[0] + rs[1] + rs[2] + rs[3];
    sq  = rq[0] + rq[1] + rq[2] + rq[3];
    const float mu   = sum * (1.0f / DIM);
    const float var  = sq * (1.0f / DIM) - mu * mu;
    const float rstd = rsqrtf(var + 1e-6f);
    out[base + tid]       = f2bf((v0 - mu) * rstd * w[tid]);
    out[base + tid + 256] = f2bf((v1 - mu) * rstd * w[tid + 256]);
    out[base + tid + 512] = f2bf((v2 - mu) * rstd * w[tid + 512]);
}

// ----------------------------------- GEMM ----------------------------------
// C[M][N] = A[M][K](bf16) x BT[N][K](bf16)^T
// EPI 0: store bf16.  EPI 1: outf = res + C (fp32).  EPI 2: store bf16(gelu(C)).
// block 256 = 4 waves (2x2), block tile 64x64, wave tile 32x32 (2x2 frags), BK=32.
template<int EPI>
__global__ __launch_bounds__(256) void gemm_bf16(
    const unsigned short* __restrict__ A,
    const unsigned short* __restrict__ BT,
    const float* __restrict__ res,
    unsigned short* __restrict__ outb,
    float* __restrict__ outf,
    int M, int N, int K)
{
    __shared__ unsigned short As[64][40];   // +8 pad: 2-way bank alias (free)
    __shared__ unsigned short Bs[64][40];
    const int tid  = threadIdx.x;
    const int wid  = tid >> 6, lane = tid & 63;
    const int bm   = blockIdx.x * 64, bn = blockIdx.y * 64;
    const int wm   = (wid >> 1) * 32, wn = (wid & 1) * 32;
    const int lr   = lane & 15;
    const int kb   = (lane >> 4) * 8;
    const int arow = tid >> 2;             // 0..63
    const int acol = (tid & 3) * 8;        // 0..24
    const size_t a_src = (size_t)(bm + arow) * K + acol;
    const size_t b_src = (size_t)(bn + arow) * K + acol;

    f32x4 acc[2][2] = {};
    for (int k0 = 0; k0 < K; k0 += 32) {
        ushort8 av = *(const ushort8*)(A  + a_src + k0);
        ushort8 bv = *(const ushort8*)(BT + b_src + k0);
        __syncthreads();
        *(ushort8*)&As[arow][acol] = av;
        *(ushort8*)&Bs[arow][acol] = bv;
        __syncthreads();
        bf16x8 a0 = *(const bf16x8*)&As[wm + lr][kb];
        bf16x8 a1 = *(const bf16x8*)&As[wm + 16 + lr][kb];
        bf16x8 b0 = *(const bf16x8*)&Bs[wn + lr][kb];
        bf16x8 b1 = *(const bf16x8*)&Bs[wn + 16 + lr][kb];
        acc[0][0] = __builtin_amdgcn_mfma_f32_16x16x32_bf16(a0, b0, acc[0][0], 0, 0, 0);
        acc[0][1] = __builtin_amdgcn_mfma_f32_16x16x32_bf16(a0, b1, acc[0][1], 0, 0, 0);
        acc[1][0] = __builtin_amdgcn_mfma_f32_16x16x32_bf16(a1, b0, acc[1][0], 0, 0, 0);
        acc[1][1] = __builtin_amdgcn_mfma_f32_16x16x32_bf16(a1, b1, acc[1][1], 0, 0, 0);
    }
#pragma unroll
    for (int i = 0; i < 2; ++i)
#pragma unroll
        for (int j = 0; j < 2; ++j)
#pragma unroll
            for (int r = 0; r < 4; ++r) {
                const int row = bm + wm + i * 16 + (lane >> 4) * 4 + r;
                const int col = bn + wn + j * 16 + lr;
                const size_t idx = (size_t)row * N + col;
                const float v = acc[i][j][r];
                if (EPI == 0) {
                    outb[idx] = f2bf(v);
                } else if (EPI == 1) {
                    outf[idx] = res[idx] + v;
                } else {
                    const float g = 0.5f * v * (1.0f + erff(v * 0.70710678118654752f));
                    outb[idx] = f2bf(g);
                }
            }
}

// ------------------------------ flash attention ----------------------------
// qkv [B*L][2304] bf16 (row: h*192 + {0:q,64:k,128:v} + d) -> o [B*L][768] bf16
// block = 256 thr (4 waves), one (b,h), 16 q rows (4/wave). K/V tiles of 64.
__global__ __launch_bounds__(256) void attn_fwd(
    const unsigned short* __restrict__ qkv, unsigned short* __restrict__ o)
{
    __shared__ float Qs[16][68];
    __shared__ float Ks[64][68];
    __shared__ float Vs[64][68];
    __shared__ float Ps[4][4][64];
    const int tid = threadIdx.x, wid = tid >> 6, lane = tid & 63;
    const int qt = blockIdx.x;              // q tile (16 rows)
    const int bh = blockIdx.y;
    const int b = bh / NHEAD, h = bh % NHEAD;
    const size_t rowbase = (size_t)b * SEQ;

    if (tid < 128) {                        // stage Q, pre-scaled
        const int row = tid >> 3, dc = (tid & 7) * 8;
        ushort8 v = *(const ushort8*)(qkv + (rowbase + qt * 16 + row) * QKVW + h * 192 + dc);
        *(f32x4*)&Qs[row][dc] = (f32x4){bf2f(v[0]), bf2f(v[1]), bf2f(v[2]), bf2f(v[3])} * ATT_SCALE;
        *(f32x4*)&Qs[row][dc + 4] = (f32x4){bf2f(v[4]), bf2f(v[5]), bf2f(v[6]), bf2f(v[7])} * ATT_SCALE;
    }

    float m[4] = {-1e30f, -1e30f, -1e30f, -1e30f};
    float l[4] = {0.f, 0.f, 0.f, 0.f};
    float Oa[4] = {0.f, 0.f, 0.f, 0.f};

    for (int kt = 0; kt < SEQ / 64; ++kt) {
        __syncthreads();
#pragma unroll
        for (int s = 0; s < 2; ++s) {       // stage K,V tile (64x64 each)
            const int idx = tid + s * 256;
            const int row = idx >> 3, dc = (idx & 7) * 8;
            const unsigned short* src = qkv + (rowbase + kt * 64 + row) * QKVW + h * 192 + 64 + dc;
            ushort8 kv = *(const ushort8*)src;
            ushort8 vv = *(const ushort8*)(src + 64);
            *(f32x4*)&Ks[row][dc]     = (f32x4){bf2f(kv[0]), bf2f(kv[1]), bf2f(kv[2]), bf2f(kv[3])};
            *(f32x4*)&Ks[row][dc + 4] = (f32x4){bf2f(kv[4]), bf2f(kv[5]), bf2f(kv[6]), bf2f(kv[7])};
            *(f32x4*)&Vs[row][dc]     = (f32x4){bf2f(vv[0]), bf2f(vv[1]), bf2f(vv[2]), bf2f(vv[3])};
            *(f32x4*)&Vs[row][dc + 4] = (f32x4){bf2f(vv[4]), bf2f(vv[5]), bf2f(vv[6]), bf2f(vv[7])};
        }
        __syncthreads();

        // QK^T: lane = key j within tile; 4 q rows per wave
        float s0 = 0.f, s1 = 0.f, s2 = 0.f, s3 = 0.f;
#pragma unroll
        for (int dc = 0; dc < 64; dc += 4) {
            f32x4 kv = *(const f32x4*)&Ks[lane][dc];
            f32x4 q0 = *(const f32x4*)&Qs[wid * 4 + 0][dc];
            f32x4 q1 = *(const f32x4*)&Qs[wid * 4 + 1][dc];
            f32x4 q2 = *(const f32x4*)&Qs[wid * 4 + 2][dc];
            f32x4 q3 = *(const f32x4*)&Qs[wid * 4 + 3][dc];
#pragma unroll
            for (int e = 0; e < 4; ++e) {
                s0 += kv[e] * q0[e];
                s1 += kv[e] * q1[e];
                s2 += kv[e] * q2[e];
                s3 += kv[e] * q3[e];
            }
        }
        float sv[4] = {s0, s1, s2, s3};
#pragma unroll
        for (int r = 0; r < 4; ++r) {
            float s = sv[r];
            float tm = s;
#pragma unroll
            for (int off = 1; off < 64; off <<= 1) tm = fmaxf(tm, __shfl_xor(tm, off));
            const float mn   = fmaxf(m[r], tm);
            const float corr = __expf(m[r] - mn);
            const float p    = __expf(s - mn);
            float ps = p;
#pragma unroll
            for (int off = 1; off < 64; off <<= 1) ps += __shfl_xor(ps, off);
            l[r] = l[r] * corr + ps;
            m[r] = mn;
            Oa[r] *= corr;
            Ps[wid][r][lane] = p;
        }
        // PV: lane = d (same-wave LDS RAW, no barrier needed)
#pragma unroll
        for (int j = 0; j < 64; j += 4) {
            f32x4 p0 = *(const f32x4*)&Ps[wid][0][j];
            f32x4 p1 = *(const f32x4*)&Ps[wid][1][j];
            f32x4 p2 = *(const f32x4*)&Ps[wid][2][j];
            f32x4 p3 = *(const f32x4*)&Ps[wid][3][j];
#pragma unroll
            for (int jj = 0; jj < 4; ++jj) {
                const float vj = Vs[j + jj][lane];
                Oa[0] += p0[jj] * vj;
                Oa[1] += p1[jj] * vj;
                Oa[2] += p2[jj] * vj;
                Oa[3] += p3[jj] * vj;
            }
        }
    }
#pragma unroll
    for (int r = 0; r < 4; ++r) {
        const int row = qt * 16 + wid * 4 + r;
        o[(rowbase + row) * DIM + h * HD + lane] = f2bf(Oa[r] / l[r]);
    }
}

// -------------------------------- launcher ---------------------------------
extern "C" void kernel_launch(void* const* d_in, const int* in_sizes, int n_in,
                              void* d_out, int out_size, void* d_ws, size_t ws_size,
                              hipStream_t stream)
{
    const float* x     = (const float*)d_in[0];
    // d_in[1] = mask, all-true -> ignored
    const float* ln1w  = (const float*)d_in[2];
    const float* ln2w  = (const float*)d_in[3];
    const float* wqkv  = (const float*)d_in[4];
    const float* wproj = (const float*)d_in[5];
    const float* wmlp1 = (const float*)d_in[6];
    const float* wmlp2 = (const float*)d_in[7];
    float* out = (float*)d_out;

    char* ws = (char*)d_ws;
    size_t off = 0;
    auto alloc = [&](size_t nbytes) -> void* {
        void* p = (void*)(ws + off);
        off += (nbytes + 255) & ~(size_t)255;
        return p;
    };
    unsigned short* hb     = (unsigned short*)alloc((size_t)ROWS * DIM  * 2);
    unsigned short* qkvb   = (unsigned short*)alloc((size_t)ROWS * QKVW * 2);
    unsigned short* ob     = (unsigned short*)alloc((size_t)ROWS * DIM  * 2);
    float*          x1     = (float*)         alloc((size_t)ROWS * DIM  * 4);
    unsigned short* h2b    = (unsigned short*)alloc((size_t)ROWS * DIM  * 2);
    unsigned short* gb     = (unsigned short*)alloc((size_t)ROWS * MLPH * 2);
    unsigned short* wqkvT  = (unsigned short*)alloc((size_t)QKVW * DIM * 2);
    unsigned short* wprojT = (unsigned short*)alloc((size_t)DIM  * DIM * 2);
    unsigned short* wmlp1T = (unsigned short*)alloc((size_t)MLPH * DIM * 2);
    unsigned short* wmlp2T = (unsigned short*)alloc((size_t)DIM  * MLPH * 2);
    // total ~89.7 MB of d_ws

    const dim3 tb(32, 8);
    transpose_cast<<<dim3(QKVW / 32, DIM / 32),  tb, 0, stream>>>(wqkv,  wqkvT,  DIM,  QKVW);
    transpose_cast<<<dim3(DIM / 32,  DIM / 32),  tb, 0, stream>>>(wproj, wprojT, DIM,  DIM);
    transpose_cast<<<dim3(MLPH / 32, DIM / 32),  tb, 0, stream>>>(wmlp1, wmlp1T, DIM,  MLPH);
    transpose_cast<<<dim3(DIM / 32,  MLPH / 32), tb, 0, stream>>>(wmlp2, wmlp2T, MLPH, DIM);

    ln_fwd<<<ROWS, 256, 0, stream>>>(x, ln1w, hb);

    gemm_bf16<0><<<dim3(ROWS / 64, QKVW / 64), 256, 0, stream>>>(
        hb, wqkvT, nullptr, qkvb, nullptr, ROWS, QKVW, DIM);

    attn_fwd<<<dim3(SEQ / 16, BATCH * NHEAD), 256, 0, stream>>>(qkvb, ob);

    gemm_bf16<1><<<dim3(ROWS / 64, DIM / 64), 256, 0, stream>>>(
        ob, wprojT, x, nullptr, x1, ROWS, DIM, DIM);

    ln_fwd<<<ROWS, 256, 0, stream>>>(x1, ln2w, h2b);

    gemm_bf16<2><<<dim3(ROWS / 64, MLPH / 64), 256, 0, stream>>>(
        h2b, wmlp1T, nullptr, gb, nullptr, ROWS, MLPH, DIM);

    gemm_bf16<1><<<dim3(ROWS / 64, DIM / 64), 256, 0, stream>>>(
        gb, wmlp2T, x1, nullptr, out, ROWS, DIM, MLPH);
}

// Round 2
// 345.721 us; speedup vs baseline: 3.2025x; 3.2025x over previous
//
#include <hip/hip_runtime.h>
#include <hip/hip_bf16.h>

// ---------------------------------------------------------------------------
// Transformer block (LN1 -> QKV -> MHA -> proj+res -> LN2 -> MLP+res)
// B=2, L=2048, D=768, H=12, hd=64, MLP=3072. fp32 in/out, bf16 MFMA inside.
// Round 2: MFMA flash attention (swapped QK^T, XOR-swizzled transposed V).
// ---------------------------------------------------------------------------

#define DIM     768
#define SEQ     2048
#define BATCH   2
#define NHEAD   12
#define HD      64
#define MLPH    3072
#define ROWS    (BATCH * SEQ)      // 4096
#define QKVW    (3 * DIM)          // 2304
#define ATT_SCALE 0.125f           // 64^-0.5

typedef __attribute__((ext_vector_type(8))) short          bf16x8;
typedef __attribute__((ext_vector_type(8))) unsigned short ushort8;
typedef __attribute__((ext_vector_type(4))) unsigned short ushort4v;
typedef __attribute__((ext_vector_type(4))) float          f32x4;

__device__ __forceinline__ float bf2f(unsigned short u) {
    union { unsigned int i; float f; } c; c.i = ((unsigned int)u) << 16; return c.f;
}
__device__ __forceinline__ unsigned short f2bf(float f) {
    union { float f; unsigned int i; } c; c.f = f;
    unsigned int i = c.i;
    return (unsigned short)((i + 0x7FFFu + ((i >> 16) & 1u)) >> 16);
}

// --------------------------- weight transpose+cast -------------------------
__global__ __launch_bounds__(256) void transpose_cast(
    const float* __restrict__ in, unsigned short* __restrict__ out, int K, int N)
{
    __shared__ float tile[32][33];
    const int n0 = blockIdx.x * 32, k0 = blockIdx.y * 32;
    const int tx = threadIdx.x, ty = threadIdx.y;   // block (32,8)
#pragma unroll
    for (int i = 0; i < 4; ++i)
        tile[ty + i * 8][tx] = in[(size_t)(k0 + ty + i * 8) * N + n0 + tx];
    __syncthreads();
#pragma unroll
    for (int i = 0; i < 4; ++i)
        out[(size_t)(n0 + ty + i * 8) * K + k0 + tx] = f2bf(tile[tx][ty + i * 8]);
}

// --------------------------------- layernorm -------------------------------
__global__ __launch_bounds__(256) void ln_fwd(
    const float* __restrict__ x, const float* __restrict__ w,
    unsigned short* __restrict__ out)
{
    const int row = blockIdx.x;
    const int tid = threadIdx.x;
    const size_t base = (size_t)row * DIM;
    float v0 = x[base + tid], v1 = x[base + tid + 256], v2 = x[base + tid + 512];
    float sum = v0 + v1 + v2;
    float sq  = v0 * v0 + v1 * v1 + v2 * v2;
#pragma unroll
    for (int off = 1; off < 64; off <<= 1) {
        sum += __shfl_xor(sum, off);
        sq  += __shfl_xor(sq,  off);
    }
    __shared__ float rs[4], rq[4];
    const int wid = tid >> 6, lane = tid & 63;
    if (lane == 0) { rs[wid] = sum; rq[wid] = sq; }
    __syncthreads();
    sum = rs[0] + rs[1] + rs[2] + rs[3];
    sq  = rq[0] + rq[1] + rq[2] + rq[3];
    const float mu   = sum * (1.0f / DIM);
    const float var  = sq * (1.0f / DIM) - mu * mu;
    const float rstd = rsqrtf(var + 1e-6f);
    out[base + tid]       = f2bf((v0 - mu) * rstd * w[tid]);
    out[base + tid + 256] = f2bf((v1 - mu) * rstd * w[tid + 256]);
    out[base + tid + 512] = f2bf((v2 - mu) * rstd * w[tid + 512]);
}

// ----------------------------------- GEMM ----------------------------------
// C[M][N] = A[M][K](bf16) x BT[N][K](bf16)^T
// EPI 0: store bf16.  EPI 1: outf = res + C (fp32).  EPI 2: store bf16(gelu(C)).
template<int EPI>
__global__ __launch_bounds__(256) void gemm_bf16(
    const unsigned short* __restrict__ A,
    const unsigned short* __restrict__ BT,
    const float* __restrict__ res,
    unsigned short* __restrict__ outb,
    float* __restrict__ outf,
    int M, int N, int K)
{
    __shared__ unsigned short As[64][40];
    __shared__ unsigned short Bs[64][40];
    const int tid  = threadIdx.x;
    const int wid  = tid >> 6, lane = tid & 63;
    const int bm   = blockIdx.x * 64, bn = blockIdx.y * 64;
    const int wm   = (wid >> 1) * 32, wn = (wid & 1) * 32;
    const int lr   = lane & 15;
    const int kb   = (lane >> 4) * 8;
    const int arow = tid >> 2;
    const int acol = (tid & 3) * 8;
    const size_t a_src = (size_t)(bm + arow) * K + acol;
    const size_t b_src = (size_t)(bn + arow) * K + acol;

    f32x4 acc[2][2] = {};
    for (int k0 = 0; k0 < K; k0 += 32) {
        ushort8 av = *(const ushort8*)(A  + a_src + k0);
        ushort8 bv = *(const ushort8*)(BT + b_src + k0);
        __syncthreads();
        *(ushort8*)&As[arow][acol] = av;
        *(ushort8*)&Bs[arow][acol] = bv;
        __syncthreads();
        bf16x8 a0 = *(const bf16x8*)&As[wm + lr][kb];
        bf16x8 a1 = *(const bf16x8*)&As[wm + 16 + lr][kb];
        bf16x8 b0 = *(const bf16x8*)&Bs[wn + lr][kb];
        bf16x8 b1 = *(const bf16x8*)&Bs[wn + 16 + lr][kb];
        acc[0][0] = __builtin_amdgcn_mfma_f32_16x16x32_bf16(a0, b0, acc[0][0], 0, 0, 0);
        acc[0][1] = __builtin_amdgcn_mfma_f32_16x16x32_bf16(a0, b1, acc[0][1], 0, 0, 0);
        acc[1][0] = __builtin_amdgcn_mfma_f32_16x16x32_bf16(a1, b0, acc[1][0], 0, 0, 0);
        acc[1][1] = __builtin_amdgcn_mfma_f32_16x16x32_bf16(a1, b1, acc[1][1], 0, 0, 0);
    }
#pragma unroll
    for (int i = 0; i < 2; ++i)
#pragma unroll
        for (int j = 0; j < 2; ++j)
#pragma unroll
            for (int r = 0; r < 4; ++r) {
                const int row = bm + wm + i * 16 + (lane >> 4) * 4 + r;
                const int col = bn + wn + j * 16 + lr;
                const size_t idx = (size_t)row * N + col;
                const float v = acc[i][j][r];
                if (EPI == 0) {
                    outb[idx] = f2bf(v);
                } else if (EPI == 1) {
                    outf[idx] = res[idx] + v;
                } else {
                    const float g = 0.5f * v * (1.0f + erff(v * 0.70710678118654752f));
                    outb[idx] = f2bf(g);
                }
            }
}

// ------------------------------ MFMA flash attention -----------------------
// qkv [B*L][2304] bf16 (row: h*192 + {0:q,64:k,128:v}) -> o [B*L][768] bf16
// Block = 256 thr (4 waves), one (b,h), 64 q rows (16/wave). KV tiles of 64.
// Swapped QK^T: S^T = mfma(A=K_tile, B=Q^T) so softmax col = q = lane&15.
// V staged transposed with XOR swizzle col = kv ^ ((d>>3)<<3) (bank-spread).
__global__ __launch_bounds__(256) void attn_mfma(
    const unsigned short* __restrict__ qkv, unsigned short* __restrict__ o)
{
    __shared__ unsigned short Ks[64][72];        // [kv][d]
    __shared__ unsigned short Vt[64][72];        // [d][kv ^ ((d>>3)<<3)]
    __shared__ unsigned short Ps[4][16][72];     // per-wave [q][kv]
    const int tid = threadIdx.x, wid = tid >> 6, lane = tid & 63;
    const int l15 = lane & 15, g = lane >> 4;
    const int qt = blockIdx.x, bh = blockIdx.y;
    const int b = bh / NHEAD, h = bh % NHEAD;
    const size_t rowbase = (size_t)b * SEQ;

    // Q B-fragments straight from global: q = l15, d = g*8 + j (+32)
    const int qrow = qt * 64 + wid * 16 + l15;
    bf16x8 qf0, qf1;
    {
        const unsigned short* qp = qkv + (rowbase + qrow) * QKVW + h * 192 + g * 8;
        qf0 = *(const bf16x8*)qp;
        qf1 = *(const bf16x8*)(qp + 32);
    }

    float m_r = -1e30f, l_r = 0.f;
    f32x4 oacc[4] = {};                          // [dt]: d = dt*16+l15, q = g*4+r

    for (int kt = 0; kt < SEQ / 64; ++kt) {
        __syncthreads();
#pragma unroll
        for (int s = 0; s < 2; ++s) {            // stage K row-major, V transposed
            const int idx = tid + s * 256;
            const int kv = idx >> 3, d0 = (idx & 7) * 8;
            const unsigned short* src = qkv + (rowbase + kt * 64 + kv) * QKVW + h * 192 + 64;
            ushort8 kvv = *(const ushort8*)(src + d0);
            ushort8 vv  = *(const ushort8*)(src + 64 + d0);
            *(ushort8*)&Ks[kv][d0] = kvv;
            const int kvs = kv ^ (((d0 >> 3) & 7) << 3);
#pragma unroll
            for (int j = 0; j < 8; ++j)
                Vt[d0 + j][kvs] = vv[j];
        }
        __syncthreads();

        // S^T tiles: kv_local = st*16 + g*4 + r, q = l15
        f32x4 sc[4];
#pragma unroll
        for (int st = 0; st < 4; ++st) {
            bf16x8 k0 = *(const bf16x8*)&Ks[st * 16 + l15][g * 8];
            bf16x8 k1 = *(const bf16x8*)&Ks[st * 16 + l15][32 + g * 8];
            f32x4 acc = {};
            acc = __builtin_amdgcn_mfma_f32_16x16x32_bf16(k0, qf0, acc, 0, 0, 0);
            acc = __builtin_amdgcn_mfma_f32_16x16x32_bf16(k1, qf1, acc, 0, 0, 0);
            sc[st] = acc * ATT_SCALE;
        }

        // online softmax for q = l15 (stats replicated across the 4 g-groups)
        float tmax = -1e30f;
#pragma unroll
        for (int st = 0; st < 4; ++st)
#pragma unroll
            for (int r = 0; r < 4; ++r) tmax = fmaxf(tmax, sc[st][r]);
        tmax = fmaxf(tmax, __shfl_xor(tmax, 16));
        tmax = fmaxf(tmax, __shfl_xor(tmax, 32));
        const float mn   = fmaxf(m_r, tmax);
        const float corr = __expf(m_r - mn);
        m_r = mn;
        float rsum = 0.f;
#pragma unroll
        for (int st = 0; st < 4; ++st) {
            ushort4v pv;
#pragma unroll
            for (int r = 0; r < 4; ++r) {
                const float p = __expf(sc[st][r] - mn);
                rsum += p;
                pv[r] = f2bf(p);
            }
            *(ushort4v*)&Ps[wid][l15][st * 16 + g * 4] = pv;  // P[q][kv]
        }
        rsum += __shfl_xor(rsum, 16);
        rsum += __shfl_xor(rsum, 32);
        l_r = l_r * corr + rsum;

        // rescale O (its q = g*4+r; corr lives at lane q for q<16)
#pragma unroll
        for (int r = 0; r < 4; ++r) {
            const float c = __shfl(corr, g * 4 + r);
#pragma unroll
            for (int dt = 0; dt < 4; ++dt) oacc[dt][r] *= c;
        }

        // PV: O[q][d] += P[q][kv] V[kv][d]
#pragma unroll
        for (int kk = 0; kk < 2; ++kk) {
            bf16x8 pf = *(const bf16x8*)&Ps[wid][l15][kk * 32 + g * 8];
#pragma unroll
            for (int dt = 0; dt < 4; ++dt) {
                const int d = dt * 16 + l15;
                const int col = (kk * 32 + g * 8) ^ (((d >> 3) & 7) << 3);
                bf16x8 vf = *(const bf16x8*)&Vt[d][col];
                oacc[dt] = __builtin_amdgcn_mfma_f32_16x16x32_bf16(pf, vf, oacc[dt], 0, 0, 0);
            }
        }
    }

#pragma unroll
    for (int r = 0; r < 4; ++r) {
        const float li  = __shfl(l_r, g * 4 + r);
        const float inv = 1.0f / li;
        const int   row = qt * 64 + wid * 16 + g * 4 + r;
#pragma unroll
        for (int dt = 0; dt < 4; ++dt)
            o[(rowbase + row) * DIM + h * HD + dt * 16 + l15] = f2bf(oacc[dt][r] * inv);
    }
}

// -------------------------------- launcher ---------------------------------
extern "C" void kernel_launch(void* const* d_in, const int* in_sizes, int n_in,
                              void* d_out, int out_size, void* d_ws, size_t ws_size,
                              hipStream_t stream)
{
    const float* x     = (const float*)d_in[0];
    const float* ln1w  = (const float*)d_in[2];
    const float* ln2w  = (const float*)d_in[3];
    const float* wqkv  = (const float*)d_in[4];
    const float* wproj = (const float*)d_in[5];
    const float* wmlp1 = (const float*)d_in[6];
    const float* wmlp2 = (const float*)d_in[7];
    float* out = (float*)d_out;

    char* ws = (char*)d_ws;
    size_t off = 0;
    auto alloc = [&](size_t nbytes) -> void* {
        void* p = (void*)(ws + off);
        off += (nbytes + 255) & ~(size_t)255;
        return p;
    };
    unsigned short* hb     = (unsigned short*)alloc((size_t)ROWS * DIM  * 2);
    unsigned short* qkvb   = (unsigned short*)alloc((size_t)ROWS * QKVW * 2);
    unsigned short* ob     = (unsigned short*)alloc((size_t)ROWS * DIM  * 2);
    float*          x1     = (float*)         alloc((size_t)ROWS * DIM  * 4);
    unsigned short* h2b    = (unsigned short*)alloc((size_t)ROWS * DIM  * 2);
    unsigned short* gb     = (unsigned short*)alloc((size_t)ROWS * MLPH * 2);
    unsigned short* wqkvT  = (unsigned short*)alloc((size_t)QKVW * DIM * 2);
    unsigned short* wprojT = (unsigned short*)alloc((size_t)DIM  * DIM * 2);
    unsigned short* wmlp1T = (unsigned short*)alloc((size_t)MLPH * DIM * 2);
    unsigned short* wmlp2T = (unsigned short*)alloc((size_t)DIM  * MLPH * 2);

    const dim3 tb(32, 8);
    transpose_cast<<<dim3(QKVW / 32, DIM / 32),  tb, 0, stream>>>(wqkv,  wqkvT,  DIM,  QKVW);
    transpose_cast<<<dim3(DIM / 32,  DIM / 32),  tb, 0, stream>>>(wproj, wprojT, DIM,  DIM);
    transpose_cast<<<dim3(MLPH / 32, DIM / 32),  tb, 0, stream>>>(wmlp1, wmlp1T, DIM,  MLPH);
    transpose_cast<<<dim3(DIM / 32,  MLPH / 32), tb, 0, stream>>>(wmlp2, wmlp2T, MLPH, DIM);

    ln_fwd<<<ROWS, 256, 0, stream>>>(x, ln1w, hb);

    gemm_bf16<0><<<dim3(ROWS / 64, QKVW / 64), 256, 0, stream>>>(
        hb, wqkvT, nullptr, qkvb, nullptr, ROWS, QKVW, DIM);

    attn_mfma<<<dim3(SEQ / 64, BATCH * NHEAD), 256, 0, stream>>>(qkvb, ob);

    gemm_bf16<1><<<dim3(ROWS / 64, DIM / 64), 256, 0, stream>>>(
        ob, wprojT, x, nullptr, x1, ROWS, DIM, DIM);

    ln_fwd<<<ROWS, 256, 0, stream>>>(x1, ln2w, h2b);

    gemm_bf16<2><<<dim3(ROWS / 64, MLPH / 64), 256, 0, stream>>>(
        h2b, wmlp1T, nullptr, gb, nullptr, ROWS, MLPH, DIM);

    gemm_bf16<1><<<dim3(ROWS / 64, DIM / 64), 256, 0, stream>>>(
        gb, wmlp2T, x1, nullptr, out, ROWS, DIM, MLPH);
}

// Round 3
// 318.140 us; speedup vs baseline: 3.4802x; 1.0867x over previous
//
#include <hip/hip_runtime.h>
#include <hip/hip_bf16.h>

// ---------------------------------------------------------------------------
// Transformer block (LN1 -> QKV -> MHA -> proj+res -> LN2 -> MLP+res)
// B=2, L=2048, D=768, H=12, hd=64, MLP=3072. fp32 in/out, bf16 MFMA inside.
// Round 3: m97-structure GEMMs (128^2 tile + global_load_lds w=16 staging for
// N>=2304 GEMMs; 64^2 + gll for N=768 GEMMs to keep grid filled).
// ---------------------------------------------------------------------------

#define DIM     768
#define SEQ     2048
#define BATCH   2
#define NHEAD   12
#define HD      64
#define MLPH    3072
#define ROWS    (BATCH * SEQ)      // 4096
#define QKVW    (3 * DIM)          // 2304
#define ATT_SCALE 0.125f           // 64^-0.5

typedef __attribute__((ext_vector_type(8))) short          bf16x8;
typedef __attribute__((ext_vector_type(8))) unsigned short ushort8;
typedef __attribute__((ext_vector_type(4))) unsigned short ushort4v;
typedef __attribute__((ext_vector_type(4))) float          f32x4;

__device__ __forceinline__ float bf2f(unsigned short u) {
    union { unsigned int i; float f; } c; c.i = ((unsigned int)u) << 16; return c.f;
}
__device__ __forceinline__ unsigned short f2bf(float f) {
    union { float f; unsigned int i; } c; c.f = f;
    unsigned int i = c.i;
    return (unsigned short)((i + 0x7FFFu + ((i >> 16) & 1u)) >> 16);
}

// async global->LDS, 16B per lane. LDS dest must be wave-uniform base;
// HW writes lane l's 16B at base + l*16.
__device__ __forceinline__ void gll16(const unsigned short* g, unsigned short* l) {
    __builtin_amdgcn_global_load_lds(
        (const __attribute__((address_space(1))) unsigned int*)g,
        (__attribute__((address_space(3))) unsigned int*)l,
        16, 0, 0);
}

// --------------------------- weight transpose+cast -------------------------
__global__ __launch_bounds__(256) void transpose_cast(
    const float* __restrict__ in, unsigned short* __restrict__ out, int K, int N)
{
    __shared__ float tile[32][33];
    const int n0 = blockIdx.x * 32, k0 = blockIdx.y * 32;
    const int tx = threadIdx.x, ty = threadIdx.y;   // block (32,8)
#pragma unroll
    for (int i = 0; i < 4; ++i)
        tile[ty + i * 8][tx] = in[(size_t)(k0 + ty + i * 8) * N + n0 + tx];
    __syncthreads();
#pragma unroll
    for (int i = 0; i < 4; ++i)
        out[(size_t)(n0 + ty + i * 8) * K + k0 + tx] = f2bf(tile[tx][ty + i * 8]);
}

// --------------------------------- layernorm -------------------------------
__global__ __launch_bounds__(256) void ln_fwd(
    const float* __restrict__ x, const float* __restrict__ w,
    unsigned short* __restrict__ out)
{
    const int row = blockIdx.x;
    const int tid = threadIdx.x;
    const size_t base = (size_t)row * DIM;
    float v0 = x[base + tid], v1 = x[base + tid + 256], v2 = x[base + tid + 512];
    float sum = v0 + v1 + v2;
    float sq  = v0 * v0 + v1 * v1 + v2 * v2;
#pragma unroll
    for (int off = 1; off < 64; off <<= 1) {
        sum += __shfl_xor(sum, off);
        sq  += __shfl_xor(sq,  off);
    }
    __shared__ float rs[4], rq[4];
    const int wid = tid >> 6, lane = tid & 63;
    if (lane == 0) { rs[wid] = sum; rq[wid] = sq; }
    __syncthreads();
    sum = rs[0] + rs[1] + rs[2] + rs[3];
    sq  = rq[0] + rq[1] + rq[2] + rq[3];
    const float mu   = sum * (1.0f / DIM);
    const float var  = sq * (1.0f / DIM) - mu * mu;
    const float rstd = rsqrtf(var + 1e-6f);
    out[base + tid]       = f2bf((v0 - mu) * rstd * w[tid]);
    out[base + tid + 256] = f2bf((v1 - mu) * rstd * w[tid + 256]);
    out[base + tid + 512] = f2bf((v2 - mu) * rstd * w[tid + 512]);
}

// ----------------------------------- GEMM ----------------------------------
// C[M][N] = A[M][K](bf16) x BT[N][K](bf16)^T, global_load_lds staging (m97).
// EPI 0: store bf16.  EPI 1: outf = res + C (fp32).  EPI 2: store bf16(gelu).
// 256 thr = 4 waves (2x2). Wave tile = (BM/2)x(BN/2). BK=32.
// LDS linear [rows][32]: wave w's gll base = row w*16; lane l -> row l/4,
// 16B chunk l%4 (matches row-major exactly -> no pad allowed, none used).
template<int EPI, int BM, int BN>
__global__ __launch_bounds__(256) void gemm_gll(
    const unsigned short* __restrict__ A,
    const unsigned short* __restrict__ BT,
    const float* __restrict__ res,
    unsigned short* __restrict__ outb,
    float* __restrict__ outf,
    int M, int N, int K)
{
    constexpr int WM = BM / 2, WN = BN / 2;
    constexpr int MI = WM / 16, NJ = WN / 16;
    __shared__ __align__(16) unsigned short As[BM * 32];
    __shared__ __align__(16) unsigned short Bs[BN * 32];
    const int tid = threadIdx.x, wid = tid >> 6;
    const int lane = tid & 63, l15 = lane & 15, g = lane >> 4;
    const int bm = blockIdx.x * BM, bn = blockIdx.y * BN;
    const int wm = (wid >> 1) * WM, wn = (wid & 1) * WN;

    const int srow = tid >> 2, scol = (tid & 3) * 8;
    const unsigned short* ag = A  + (size_t)(bm + srow) * K + scol;
    const unsigned short* bg = BT + (size_t)(bn + srow) * K + scol;
    unsigned short* al = &As[wid * 16 * 32];
    unsigned short* bl = &Bs[wid * 16 * 32];

    f32x4 acc[MI][NJ] = {};
    for (int k0 = 0; k0 < K; k0 += 32) {
#pragma unroll
        for (int s = 0; s < BM / 64; ++s)
            gll16(ag + (size_t)(s * 64) * K + k0, al + s * 64 * 32);
#pragma unroll
        for (int s = 0; s < BN / 64; ++s)
            gll16(bg + (size_t)(s * 64) * K + k0, bl + s * 64 * 32);
        __syncthreads();   // drains vmcnt -> LDS tile ready
        bf16x8 af[MI], bfr[NJ];
#pragma unroll
        for (int i = 0; i < MI; ++i)
            af[i] = *(const bf16x8*)&As[(wm + i * 16 + l15) * 32 + g * 8];
#pragma unroll
        for (int j = 0; j < NJ; ++j)
            bfr[j] = *(const bf16x8*)&Bs[(wn + j * 16 + l15) * 32 + g * 8];
#pragma unroll
        for (int i = 0; i < MI; ++i)
#pragma unroll
            for (int j = 0; j < NJ; ++j)
                acc[i][j] = __builtin_amdgcn_mfma_f32_16x16x32_bf16(
                    af[i], bfr[j], acc[i][j], 0, 0, 0);
        __syncthreads();   // all reads done before next stage overwrites
    }
#pragma unroll
    for (int i = 0; i < MI; ++i)
#pragma unroll
        for (int j = 0; j < NJ; ++j)
#pragma unroll
            for (int r = 0; r < 4; ++r) {
                const int row = bm + wm + i * 16 + g * 4 + r;
                const int col = bn + wn + j * 16 + l15;
                const size_t idx = (size_t)row * N + col;
                const float v = acc[i][j][r];
                if (EPI == 0) {
                    outb[idx] = f2bf(v);
                } else if (EPI == 1) {
                    outf[idx] = res[idx] + v;
                } else {
                    const float gl = 0.5f * v * (1.0f + erff(v * 0.70710678118654752f));
                    outb[idx] = f2bf(gl);
                }
            }
}

// ------------------------------ MFMA flash attention -----------------------
// qkv [B*L][2304] bf16 (row: h*192 + {0:q,64:k,128:v}) -> o [B*L][768] bf16
// Block = 256 thr (4 waves), one (b,h), 64 q rows (16/wave). KV tiles of 64.
// Swapped QK^T: S^T = mfma(A=K_tile, B=Q^T) so softmax col = q = lane&15.
// V staged transposed with XOR swizzle col = kv ^ ((d>>3)<<3) (bank-spread).
__global__ __launch_bounds__(256) void attn_mfma(
    const unsigned short* __restrict__ qkv, unsigned short* __restrict__ o)
{
    __shared__ unsigned short Ks[64][72];        // [kv][d]
    __shared__ unsigned short Vt[64][72];        // [d][kv ^ ((d>>3)<<3)]
    __shared__ unsigned short Ps[4][16][72];     // per-wave [q][kv]
    const int tid = threadIdx.x, wid = tid >> 6, lane = tid & 63;
    const int l15 = lane & 15, g = lane >> 4;
    const int qt = blockIdx.x, bh = blockIdx.y;
    const int b = bh / NHEAD, h = bh % NHEAD;
    const size_t rowbase = (size_t)b * SEQ;

    // Q B-fragments straight from global: q = l15, d = g*8 + j (+32)
    const int qrow = qt * 64 + wid * 16 + l15;
    bf16x8 qf0, qf1;
    {
        const unsigned short* qp = qkv + (rowbase + qrow) * QKVW + h * 192 + g * 8;
        qf0 = *(const bf16x8*)qp;
        qf1 = *(const bf16x8*)(qp + 32);
    }

    float m_r = -1e30f, l_r = 0.f;
    f32x4 oacc[4] = {};                          // [dt]: d = dt*16+l15, q = g*4+r

    for (int kt = 0; kt < SEQ / 64; ++kt) {
        __syncthreads();
#pragma unroll
        for (int s = 0; s < 2; ++s) {            // stage K row-major, V transposed
            const int idx = tid + s * 256;
            const int kv = idx >> 3, d0 = (idx & 7) * 8;
            const unsigned short* src = qkv + (rowbase + kt * 64 + kv) * QKVW + h * 192 + 64;
            ushort8 kvv = *(const ushort8*)(src + d0);
            ushort8 vv  = *(const ushort8*)(src + 64 + d0);
            *(ushort8*)&Ks[kv][d0] = kvv;
            const int kvs = kv ^ (((d0 >> 3) & 7) << 3);
#pragma unroll
            for (int j = 0; j < 8; ++j)
                Vt[d0 + j][kvs] = vv[j];
        }
        __syncthreads();

        // S^T tiles: kv_local = st*16 + g*4 + r, q = l15
        f32x4 sc[4];
#pragma unroll
        for (int st = 0; st < 4; ++st) {
            bf16x8 k0 = *(const bf16x8*)&Ks[st * 16 + l15][g * 8];
            bf16x8 k1 = *(const bf16x8*)&Ks[st * 16 + l15][32 + g * 8];
            f32x4 acc = {};
            acc = __builtin_amdgcn_mfma_f32_16x16x32_bf16(k0, qf0, acc, 0, 0, 0);
            acc = __builtin_amdgcn_mfma_f32_16x16x32_bf16(k1, qf1, acc, 0, 0, 0);
            sc[st] = acc * ATT_SCALE;
        }

        // online softmax for q = l15 (stats replicated across the 4 g-groups)
        float tmax = -1e30f;
#pragma unroll
        for (int st = 0; st < 4; ++st)
#pragma unroll
            for (int r = 0; r < 4; ++r) tmax = fmaxf(tmax, sc[st][r]);
        tmax = fmaxf(tmax, __shfl_xor(tmax, 16));
        tmax = fmaxf(tmax, __shfl_xor(tmax, 32));
        const float mn   = fmaxf(m_r, tmax);
        const float corr = __expf(m_r - mn);
        m_r = mn;
        float rsum = 0.f;
#pragma unroll
        for (int st = 0; st < 4; ++st) {
            ushort4v pv;
#pragma unroll
            for (int r = 0; r < 4; ++r) {
                const float p = __expf(sc[st][r] - mn);
                rsum += p;
                pv[r] = f2bf(p);
            }
            *(ushort4v*)&Ps[wid][l15][st * 16 + g * 4] = pv;  // P[q][kv]
        }
        rsum += __shfl_xor(rsum, 16);
        rsum += __shfl_xor(rsum, 32);
        l_r = l_r * corr + rsum;

        // rescale O (its q = g*4+r; corr lives at lane q for q<16)
#pragma unroll
        for (int r = 0; r < 4; ++r) {
            const float c = __shfl(corr, g * 4 + r);
#pragma unroll
            for (int dt = 0; dt < 4; ++dt) oacc[dt][r] *= c;
        }

        // PV: O[q][d] += P[q][kv] V[kv][d]
#pragma unroll
        for (int kk = 0; kk < 2; ++kk) {
            bf16x8 pf = *(const bf16x8*)&Ps[wid][l15][kk * 32 + g * 8];
#pragma unroll
            for (int dt = 0; dt < 4; ++dt) {
                const int d = dt * 16 + l15;
                const int col = (kk * 32 + g * 8) ^ (((d >> 3) & 7) << 3);
                bf16x8 vf = *(const bf16x8*)&Vt[d][col];
                oacc[dt] = __builtin_amdgcn_mfma_f32_16x16x32_bf16(pf, vf, oacc[dt], 0, 0, 0);
            }
        }
    }

#pragma unroll
    for (int r = 0; r < 4; ++r) {
        const float li  = __shfl(l_r, g * 4 + r);
        const float inv = 1.0f / li;
        const int   row = qt * 64 + wid * 16 + g * 4 + r;
#pragma unroll
        for (int dt = 0; dt < 4; ++dt)
            o[(rowbase + row) * DIM + h * HD + dt * 16 + l15] = f2bf(oacc[dt][r] * inv);
    }
}

// -------------------------------- launcher ---------------------------------
extern "C" void kernel_launch(void* const* d_in, const int* in_sizes, int n_in,
                              void* d_out, int out_size, void* d_ws, size_t ws_size,
                              hipStream_t stream)
{
    const float* x     = (const float*)d_in[0];
    const float* ln1w  = (const float*)d_in[2];
    const float* ln2w  = (const float*)d_in[3];
    const float* wqkv  = (const float*)d_in[4];
    const float* wproj = (const float*)d_in[5];
    const float* wmlp1 = (const float*)d_in[6];
    const float* wmlp2 = (const float*)d_in[7];
    float* out = (float*)d_out;

    char* ws = (char*)d_ws;
    size_t off = 0;
    auto alloc = [&](size_t nbytes) -> void* {
        void* p = (void*)(ws + off);
        off += (nbytes + 255) & ~(size_t)255;
        return p;
    };
    unsigned short* hb     = (unsigned short*)alloc((size_t)ROWS * DIM  * 2);
    unsigned short* qkvb   = (unsigned short*)alloc((size_t)ROWS * QKVW * 2);
    unsigned short* ob     = (unsigned short*)alloc((size_t)ROWS * DIM  * 2);
    float*          x1     = (float*)         alloc((size_t)ROWS * DIM  * 4);
    unsigned short* h2b    = (unsigned short*)alloc((size_t)ROWS * DIM  * 2);
    unsigned short* gb     = (unsigned short*)alloc((size_t)ROWS * MLPH * 2);
    unsigned short* wqkvT  = (unsigned short*)alloc((size_t)QKVW * DIM * 2);
    unsigned short* wprojT = (unsigned short*)alloc((size_t)DIM  * DIM * 2);
    unsigned short* wmlp1T = (unsigned short*)alloc((size_t)MLPH * DIM * 2);
    unsigned short* wmlp2T = (unsigned short*)alloc((size_t)DIM  * MLPH * 2);

    const dim3 tb(32, 8);
    transpose_cast<<<dim3(QKVW / 32, DIM / 32),  tb, 0, stream>>>(wqkv,  wqkvT,  DIM,  QKVW);
    transpose_cast<<<dim3(DIM / 32,  DIM / 32),  tb, 0, stream>>>(wproj, wprojT, DIM,  DIM);
    transpose_cast<<<dim3(MLPH / 32, DIM / 32),  tb, 0, stream>>>(wmlp1, wmlp1T, DIM,  MLPH);
    transpose_cast<<<dim3(DIM / 32,  MLPH / 32), tb, 0, stream>>>(wmlp2, wmlp2T, MLPH, DIM);

    ln_fwd<<<ROWS, 256, 0, stream>>>(x, ln1w, hb);

    gemm_gll<0, 128, 128><<<dim3(ROWS / 128, QKVW / 128), 256, 0, stream>>>(
        hb, wqkvT, nullptr, qkvb, nullptr, ROWS, QKVW, DIM);

    attn_mfma<<<dim3(SEQ / 64, BATCH * NHEAD), 256, 0, stream>>>(qkvb, ob);

    gemm_gll<1, 64, 64><<<dim3(ROWS / 64, DIM / 64), 256, 0, stream>>>(
        ob, wprojT, x, nullptr, x1, ROWS, DIM, DIM);

    ln_fwd<<<ROWS, 256, 0, stream>>>(x1, ln2w, h2b);

    gemm_gll<2, 128, 128><<<dim3(ROWS / 128, MLPH / 128), 256, 0, stream>>>(
        h2b, wmlp1T, nullptr, gb, nullptr, ROWS, MLPH, DIM);

    gemm_gll<1, 64, 64><<<dim3(ROWS / 64, DIM / 64), 256, 0, stream>>>(
        gb, wmlp2T, x1, nullptr, out, ROWS, DIM, MLPH);
}

// Round 4
// 302.935 us; speedup vs baseline: 3.6549x; 1.0502x over previous
//
#include <hip/hip_runtime.h>
#include <hip/hip_bf16.h>

// ---------------------------------------------------------------------------
// Transformer block (LN1 -> QKV -> MHA -> proj+res -> LN2 -> MLP+res)
// B=2, L=2048, D=768, H=12, hd=64, MLP=3072. fp32 in/out, bf16 MFMA inside.
// Round 4: 2-phase dbuf gll GEMMs (issue-early, 1 barrier/step); QKV epilogue
// writes V^T[b][h][d][L]; attention reg-prefetch dbuf (1 barrier/tile), no
// scalar V transpose, cvt_pk P-pack.
// ---------------------------------------------------------------------------

#define DIM     768
#define SEQ     2048
#define BATCH   2
#define NHEAD   12
#define HD      64
#define MLPH    3072
#define ROWS    (BATCH * SEQ)      // 4096
#define QKVW    (3 * DIM)          // 2304
#define ATT_SCALE 0.125f           // 64^-0.5

typedef __attribute__((ext_vector_type(8))) short          bf16x8;
typedef __attribute__((ext_vector_type(8))) unsigned short ushort8;
typedef __attribute__((ext_vector_type(4))) unsigned short ushort4v;
typedef __attribute__((ext_vector_type(2))) unsigned int   u32x2;
typedef __attribute__((ext_vector_type(4))) float          f32x4;

__device__ __forceinline__ float bf2f(unsigned short u) {
    union { unsigned int i; float f; } c; c.i = ((unsigned int)u) << 16; return c.f;
}
__device__ __forceinline__ unsigned short f2bf(float f) {
    union { float f; unsigned int i; } c; c.f = f;
    unsigned int i = c.i;
    return (unsigned short)((i + 0x7FFFu + ((i >> 16) & 1u)) >> 16);
}
__device__ __forceinline__ unsigned int cvt_pk_bf16(float lo, float hi) {
    unsigned int r;
    asm volatile("v_cvt_pk_bf16_f32 %0, %1, %2" : "=v"(r) : "v"(lo), "v"(hi));
    return r;
}

// async global->LDS, 16B per lane: lane l writes LDS base + l*16 (linear).
__device__ __forceinline__ void gll16(const unsigned short* g, unsigned short* l) {
    __builtin_amdgcn_global_load_lds(
        (const __attribute__((address_space(1))) unsigned int*)g,
        (__attribute__((address_space(3))) unsigned int*)l,
        16, 0, 0);
}

// --------------------------- weight transpose+cast -------------------------
__global__ __launch_bounds__(256) void transpose_cast(
    const float* __restrict__ in, unsigned short* __restrict__ out, int K, int N)
{
    __shared__ float tile[32][33];
    const int n0 = blockIdx.x * 32, k0 = blockIdx.y * 32;
    const int tx = threadIdx.x, ty = threadIdx.y;   // block (32,8)
#pragma unroll
    for (int i = 0; i < 4; ++i)
        tile[ty + i * 8][tx] = in[(size_t)(k0 + ty + i * 8) * N + n0 + tx];
    __syncthreads();
#pragma unroll
    for (int i = 0; i < 4; ++i)
        out[(size_t)(n0 + ty + i * 8) * K + k0 + tx] = f2bf(tile[tx][ty + i * 8]);
}

// --------------------------------- layernorm -------------------------------
__global__ __launch_bounds__(256) void ln_fwd(
    const float* __restrict__ x, const float* __restrict__ w,
    unsigned short* __restrict__ out)
{
    const int row = blockIdx.x;
    const int tid = threadIdx.x;
    const size_t base = (size_t)row * DIM;
    float v0 = x[base + tid], v1 = x[base + tid + 256], v2 = x[base + tid + 512];
    float sum = v0 + v1 + v2;
    float sq  = v0 * v0 + v1 * v1 + v2 * v2;
#pragma unroll
    for (int off = 1; off < 64; off <<= 1) {
        sum += __shfl_xor(sum, off);
        sq  += __shfl_xor(sq,  off);
    }
    __shared__ float rs[4], rq[4];
    const int wid = tid >> 6, lane = tid & 63;
    if (lane == 0) { rs[wid] = sum; rq[wid] = sq; }
    __syncthreads();
    sum = rs[0] + rs[1] + rs[2] + rs[3];
    sq  = rq[0] + rq[1] + rq[2] + rq[3];
    const float mu   = sum * (1.0f / DIM);
    const float var  = sq * (1.0f / DIM) - mu * mu;
    const float rstd = rsqrtf(var + 1e-6f);
    out[base + tid]       = f2bf((v0 - mu) * rstd * w[tid]);
    out[base + tid + 256] = f2bf((v1 - mu) * rstd * w[tid + 256]);
    out[base + tid + 512] = f2bf((v2 - mu) * rstd * w[tid + 512]);
}

// ----------------------------------- GEMM ----------------------------------
// C[M][N] = A[M][K](bf16) x BT[N][K](bf16)^T, 2-phase dbuf gll staging.
// EPI 1: outf = res + C.  EPI 2: outb = bf16(gelu(C)).
// EPI 3 (QKV): q/k cols -> outb (qkv layout); v cols -> vt[b][h][d][L].
// 256 thr = 4 waves (2x2). Wave tile (BM/2)x(BN/2). BK=32. 1 barrier/step.
template<int EPI, int BM, int BN>
__global__ __launch_bounds__(256) void gemm_gll(
    const unsigned short* __restrict__ A,
    const unsigned short* __restrict__ BT,
    const float* __restrict__ res,
    unsigned short* __restrict__ outb,
    float* __restrict__ outf,
    unsigned short* __restrict__ vt,
    int M, int N, int K)
{
    constexpr int WM = BM / 2, WN = BN / 2;
    constexpr int MI = WM / 16, NJ = WN / 16;
    __shared__ __align__(16) unsigned short As[2][BM * 32];
    __shared__ __align__(16) unsigned short Bs[2][BN * 32];
    const int tid = threadIdx.x, wid = tid >> 6;
    const int lane = tid & 63, l15 = lane & 15, g = lane >> 4;
    const int bm = blockIdx.x * BM, bn = blockIdx.y * BN;
    const int wm = (wid >> 1) * WM, wn = (wid & 1) * WN;

    const int srow = tid >> 2, scol = (tid & 3) * 8;
    const unsigned short* ag = A  + (size_t)(bm + srow) * K + scol;
    const unsigned short* bg = BT + (size_t)(bn + srow) * K + scol;

    auto stage = [&](int buf, int k0) {
#pragma unroll
        for (int s = 0; s < BM / 64; ++s)
            gll16(ag + (size_t)(s * 64) * K + k0, &As[buf][wid * 16 * 32 + s * 64 * 32]);
#pragma unroll
        for (int s = 0; s < BN / 64; ++s)
            gll16(bg + (size_t)(s * 64) * K + k0, &Bs[buf][wid * 16 * 32 + s * 64 * 32]);
    };

    f32x4 acc[MI][NJ] = {};
    stage(0, 0);
    __syncthreads();          // prologue drain
    int cur = 0;
    for (int k0 = 0; k0 < K; k0 += 32) {
        if (k0 + 32 < K) stage(cur ^ 1, k0 + 32);   // issue-early: hidden by compute
        bf16x8 af[MI], bfr[NJ];
#pragma unroll
        for (int i = 0; i < MI; ++i)
            af[i] = *(const bf16x8*)&As[cur][(wm + i * 16 + l15) * 32 + g * 8];
#pragma unroll
        for (int j = 0; j < NJ; ++j)
            bfr[j] = *(const bf16x8*)&Bs[cur][(wn + j * 16 + l15) * 32 + g * 8];
#pragma unroll
        for (int i = 0; i < MI; ++i)
#pragma unroll
            for (int j = 0; j < NJ; ++j)
                acc[i][j] = __builtin_amdgcn_mfma_f32_16x16x32_bf16(
                    af[i], bfr[j], acc[i][j], 0, 0, 0);
        __syncthreads();      // drains this step's gll; guards buf reuse
        cur ^= 1;
    }
#pragma unroll
    for (int i = 0; i < MI; ++i)
#pragma unroll
        for (int j = 0; j < NJ; ++j) {
            const int row0 = bm + wm + i * 16 + g * 4;
            const int col  = bn + wn + j * 16 + l15;
            if (EPI == 3) {
                const int col0 = bn + wn + j * 16;     // wave-uniform
                const int rem0 = col0 % 192;
                if (rem0 < 128) {                      // q or k -> qkv layout
#pragma unroll
                    for (int r = 0; r < 4; ++r)
                        outb[(size_t)(row0 + r) * N + col] = f2bf(acc[i][j][r]);
                } else {                               // v -> vT[b][h][d][L]
                    const int hh = col0 / 192;
                    const int d  = rem0 - 128 + l15;
                    const int bb = row0 >> 11, ls = row0 & 2047;
                    ushort4v pv4;
#pragma unroll
                    for (int r = 0; r < 4; ++r) pv4[r] = f2bf(acc[i][j][r]);
                    *(ushort4v*)&vt[(((size_t)bb * NHEAD + hh) * HD + d) * SEQ + ls] = pv4;
                }
            } else {
#pragma unroll
                for (int r = 0; r < 4; ++r) {
                    const size_t idx = (size_t)(row0 + r) * N + col;
                    const float v = acc[i][j][r];
                    if (EPI == 1) {
                        outf[idx] = res[idx] + v;
                    } else if (EPI == 2) {
                        outb[idx] = f2bf(0.5f * v * (1.0f + erff(v * 0.70710678118654752f)));
                    } else {
                        outb[idx] = f2bf(v);
                    }
                }
            }
        }
}

// ------------------------------ MFMA flash attention -----------------------
// K from qkv (row-major), V from vT[b][h][d][L] (already transposed).
// Block = 256 thr (4 waves), one (b,h), 64 q rows (16/wave). KV tiles of 64.
// Reg-prefetch double-buffer, ONE barrier per tile.
// Swapped QK^T: S^T = mfma(A=K_tile, B=Q^T) so softmax col = q = lane&15.
__global__ __launch_bounds__(256) void attn_mfma(
    const unsigned short* __restrict__ qkv,
    const unsigned short* __restrict__ vT,
    unsigned short* __restrict__ o)
{
    __shared__ unsigned short Ks[2][64][72];     // [buf][kv][d]
    __shared__ unsigned short Vs[2][64][72];     // [buf][d][kv]  (V^T tile)
    __shared__ unsigned short Ps[4][16][72];     // per-wave [q][kv]
    const int tid = threadIdx.x, wid = tid >> 6, lane = tid & 63;
    const int l15 = lane & 15, g = lane >> 4;
    const int qt = blockIdx.x, bh = blockIdx.y;
    const int b = bh / NHEAD, h = bh % NHEAD;
    const size_t rowbase = (size_t)b * SEQ;

    // Q B-fragments straight from global: q = l15, d = g*8 + j (+32)
    const int qrow = qt * 64 + wid * 16 + l15;
    bf16x8 qf0, qf1;
    {
        const unsigned short* qp = qkv + (rowbase + qrow) * QKVW + h * 192 + g * 8;
        qf0 = *(const bf16x8*)qp;
        qf1 = *(const bf16x8*)(qp + 32);
    }

    // staging: thread covers rows srow, srow+32 (chunk sc..sc+7) of each tile
    const int srow = tid >> 3, sc = (tid & 7) * 8;
    const unsigned short* kg = qkv + (rowbase + srow) * QKVW + h * 192 + 64 + sc;
    const unsigned short* vg = vT + ((size_t)bh * HD + srow) * SEQ + sc;
    const size_t kstep = (size_t)64 * QKVW;

    float m_r = -1e30f, l_r = 0.f;
    f32x4 oacc[4] = {};                          // [dt]: d = dt*16+l15, q = g*4+r

    // prologue: stage tile 0 into buf 0
    ushort8 ka0 = *(const ushort8*)(kg);
    ushort8 ka1 = *(const ushort8*)(kg + 32 * QKVW);
    ushort8 va0 = *(const ushort8*)(vg);
    ushort8 va1 = *(const ushort8*)(vg + 32 * SEQ);
    *(ushort8*)&Ks[0][srow][sc]      = ka0;
    *(ushort8*)&Ks[0][srow + 32][sc] = ka1;
    *(ushort8*)&Vs[0][srow][sc]      = va0;
    *(ushort8*)&Vs[0][srow + 32][sc] = va1;
    __syncthreads();
    int cur = 0;

    for (int kt = 0; kt < SEQ / 64; ++kt) {
        const bool pf = (kt + 1 < SEQ / 64);
        if (pf) {                                // issue next tile's loads early
            const unsigned short* kp = kg + (size_t)(kt + 1) * kstep;
            const unsigned short* vp = vg + (kt + 1) * 64;
            ka0 = *(const ushort8*)(kp);
            ka1 = *(const ushort8*)(kp + 32 * QKVW);
            va0 = *(const ushort8*)(vp);
            va1 = *(const ushort8*)(vp + 32 * SEQ);
        }

        // S^T tiles: kv_local = st*16 + g*4 + r, q = l15
        f32x4 sc4[4];
#pragma unroll
        for (int st = 0; st < 4; ++st) {
            bf16x8 k0 = *(const bf16x8*)&Ks[cur][st * 16 + l15][g * 8];
            bf16x8 k1 = *(const bf16x8*)&Ks[cur][st * 16 + l15][32 + g * 8];
            f32x4 acc = {};
            acc = __builtin_amdgcn_mfma_f32_16x16x32_bf16(k0, qf0, acc, 0, 0, 0);
            acc = __builtin_amdgcn_mfma_f32_16x16x32_bf16(k1, qf1, acc, 0, 0, 0);
            sc4[st] = acc * ATT_SCALE;
        }

        // online softmax for q = l15 (stats replicated across the 4 g-groups)
        float tmax = -1e30f;
#pragma unroll
        for (int st = 0; st < 4; ++st)
#pragma unroll
            for (int r = 0; r < 4; ++r) tmax = fmaxf(tmax, sc4[st][r]);
        tmax = fmaxf(tmax, __shfl_xor(tmax, 16));
        tmax = fmaxf(tmax, __shfl_xor(tmax, 32));
        const float mn   = fmaxf(m_r, tmax);
        const float corr = __expf(m_r - mn);
        m_r = mn;
        float rsum = 0.f;
#pragma unroll
        for (int st = 0; st < 4; ++st) {
            const float p0 = __expf(sc4[st][0] - mn);
            const float p1 = __expf(sc4[st][1] - mn);
            const float p2 = __expf(sc4[st][2] - mn);
            const float p3 = __expf(sc4[st][3] - mn);
            rsum += (p0 + p1) + (p2 + p3);
            u32x2 w;
            w[0] = cvt_pk_bf16(p0, p1);
            w[1] = cvt_pk_bf16(p2, p3);
            *(u32x2*)&Ps[wid][l15][st * 16 + g * 4] = w;   // P[q][kv]
        }
        rsum += __shfl_xor(rsum, 16);
        rsum += __shfl_xor(rsum, 32);
        l_r = l_r * corr + rsum;

        // rescale O (its q = g*4+r; corr lives at lane q for q<16)
#pragma unroll
        for (int r = 0; r < 4; ++r) {
            const float c = __shfl(corr, g * 4 + r);
#pragma unroll
            for (int dt = 0; dt < 4; ++dt) oacc[dt][r] *= c;
        }

        // PV: O[q][d] += P[q][kv] V[kv][d]; V^T rows read as b128
#pragma unroll
        for (int kk = 0; kk < 2; ++kk) {
            bf16x8 pfr = *(const bf16x8*)&Ps[wid][l15][kk * 32 + g * 8];
#pragma unroll
            for (int dt = 0; dt < 4; ++dt) {
                bf16x8 vf = *(const bf16x8*)&Vs[cur][dt * 16 + l15][kk * 32 + g * 8];
                oacc[dt] = __builtin_amdgcn_mfma_f32_16x16x32_bf16(pfr, vf, oacc[dt], 0, 0, 0);
            }
        }

        if (pf) {                                // write next tile to other buf
            *(ushort8*)&Ks[cur ^ 1][srow][sc]      = ka0;
            *(ushort8*)&Ks[cur ^ 1][srow + 32][sc] = ka1;
            *(ushort8*)&Vs[cur ^ 1][srow][sc]      = va0;
            *(ushort8*)&Vs[cur ^ 1][srow + 32][sc] = va1;
        }
        __syncthreads();                         // one barrier per tile
        cur ^= 1;
    }

#pragma unroll
    for (int r = 0; r < 4; ++r) {
        const float li  = __shfl(l_r, g * 4 + r);
        const float inv = 1.0f / li;
        const int   row = qt * 64 + wid * 16 + g * 4 + r;
#pragma unroll
        for (int dt = 0; dt < 4; ++dt)
            o[(rowbase + row) * DIM + h * HD + dt * 16 + l15] = f2bf(oacc[dt][r] * inv);
    }
}

// -------------------------------- launcher ---------------------------------
extern "C" void kernel_launch(void* const* d_in, const int* in_sizes, int n_in,
                              void* d_out, int out_size, void* d_ws, size_t ws_size,
                              hipStream_t stream)
{
    const float* x     = (const float*)d_in[0];
    const float* ln1w  = (const float*)d_in[2];
    const float* ln2w  = (const float*)d_in[3];
    const float* wqkv  = (const float*)d_in[4];
    const float* wproj = (const float*)d_in[5];
    const float* wmlp1 = (const float*)d_in[6];
    const float* wmlp2 = (const float*)d_in[7];
    float* out = (float*)d_out;

    char* ws = (char*)d_ws;
    size_t off = 0;
    auto alloc = [&](size_t nbytes) -> void* {
        void* p = (void*)(ws + off);
        off += (nbytes + 255) & ~(size_t)255;
        return p;
    };
    unsigned short* hb     = (unsigned short*)alloc((size_t)ROWS * DIM  * 2);
    unsigned short* qkvb   = (unsigned short*)alloc((size_t)ROWS * QKVW * 2);
    unsigned short* vt     = (unsigned short*)alloc((size_t)BATCH * NHEAD * HD * SEQ * 2);
    unsigned short* ob     = (unsigned short*)alloc((size_t)ROWS * DIM  * 2);
    float*          x1     = (float*)         alloc((size_t)ROWS * DIM  * 4);
    unsigned short* h2b    = (unsigned short*)alloc((size_t)ROWS * DIM  * 2);
    unsigned short* gb     = (unsigned short*)alloc((size_t)ROWS * MLPH * 2);
    unsigned short* wqkvT  = (unsigned short*)alloc((size_t)QKVW * DIM * 2);
    unsigned short* wprojT = (unsigned short*)alloc((size_t)DIM  * DIM * 2);
    unsigned short* wmlp1T = (unsigned short*)alloc((size_t)MLPH * DIM * 2);
    unsigned short* wmlp2T = (unsigned short*)alloc((size_t)DIM  * MLPH * 2);

    const dim3 tb(32, 8);
    transpose_cast<<<dim3(QKVW / 32, DIM / 32),  tb, 0, stream>>>(wqkv,  wqkvT,  DIM,  QKVW);
    transpose_cast<<<dim3(DIM / 32,  DIM / 32),  tb, 0, stream>>>(wproj, wprojT, DIM,  DIM);
    transpose_cast<<<dim3(MLPH / 32, DIM / 32),  tb, 0, stream>>>(wmlp1, wmlp1T, DIM,  MLPH);
    transpose_cast<<<dim3(DIM / 32,  MLPH / 32), tb, 0, stream>>>(wmlp2, wmlp2T, MLPH, DIM);

    ln_fwd<<<ROWS, 256, 0, stream>>>(x, ln1w, hb);

    gemm_gll<3, 128, 128><<<dim3(ROWS / 128, QKVW / 128), 256, 0, stream>>>(
        hb, wqkvT, nullptr, qkvb, nullptr, vt, ROWS, QKVW, DIM);

    attn_mfma<<<dim3(SEQ / 64, BATCH * NHEAD), 256, 0, stream>>>(qkvb, vt, ob);

    gemm_gll<1, 64, 64><<<dim3(ROWS / 64, DIM / 64), 256, 0, stream>>>(
        ob, wprojT, x, nullptr, x1, nullptr, ROWS, DIM, DIM);

    ln_fwd<<<ROWS, 256, 0, stream>>>(x1, ln2w, h2b);

    gemm_gll<2, 128, 128><<<dim3(ROWS / 128, MLPH / 128), 256, 0, stream>>>(
        h2b, wmlp1T, nullptr, gb, nullptr, nullptr, ROWS, MLPH, DIM);

    gemm_gll<1, 64, 64><<<dim3(ROWS / 64, DIM / 64), 256, 0, stream>>>(
        gb, wmlp2T, x1, nullptr, out, nullptr, ROWS, DIM, MLPH);
}

// Round 5
// 302.642 us; speedup vs baseline: 3.6584x; 1.0010x over previous
//
#include <hip/hip_runtime.h>
#include <hip/hip_bf16.h>

// ---------------------------------------------------------------------------
// Transformer block (LN1 -> QKV -> MHA -> proj+res -> LN2 -> MLP+res)
// B=2, L=2048, D=768, H=12, hd=64, MLP=3072. fp32 in/out, bf16 MFMA inside.
// Round 5: GEMMs -> 3-stage LDS rotation with raw s_barrier + counted
// s_waitcnt vmcnt(N) (T4: loads never drained to 0 in-loop). Fused transposes.
// ---------------------------------------------------------------------------

#define DIM     768
#define SEQ     2048
#define BATCH   2
#define NHEAD   12
#define HD      64
#define MLPH    3072
#define ROWS    (BATCH * SEQ)      // 4096
#define QKVW    (3 * DIM)          // 2304
#define ATT_SCALE 0.125f           // 64^-0.5

typedef __attribute__((ext_vector_type(8))) short          bf16x8;
typedef __attribute__((ext_vector_type(8))) unsigned short ushort8;
typedef __attribute__((ext_vector_type(4))) unsigned short ushort4v;
typedef __attribute__((ext_vector_type(2))) unsigned int   u32x2;
typedef __attribute__((ext_vector_type(4))) float          f32x4;

__device__ __forceinline__ float bf2f(unsigned short u) {
    union { unsigned int i; float f; } c; c.i = ((unsigned int)u) << 16; return c.f;
}
__device__ __forceinline__ unsigned short f2bf(float f) {
    union { float f; unsigned int i; } c; c.f = f;
    unsigned int i = c.i;
    return (unsigned short)((i + 0x7FFFu + ((i >> 16) & 1u)) >> 16);
}
__device__ __forceinline__ unsigned int cvt_pk_bf16(float lo, float hi) {
    unsigned int r;
    asm volatile("v_cvt_pk_bf16_f32 %0, %1, %2" : "=v"(r) : "v"(lo), "v"(hi));
    return r;
}

// async global->LDS, 16B per lane: lane l writes LDS base + l*16 (linear).
__device__ __forceinline__ void gll16(const unsigned short* g, unsigned short* l) {
    __builtin_amdgcn_global_load_lds(
        (const __attribute__((address_space(1))) unsigned int*)g,
        (__attribute__((address_space(3))) unsigned int*)l,
        16, 0, 0);
}

// --------------------- fused weight transpose+cast (one launch) ------------
// each 32x32 tile of each of the 4 weights; [K][N] fp32 -> [N][K] bf16.
__global__ __launch_bounds__(256) void transpose_cast_all(
    const float* __restrict__ w0, unsigned short* __restrict__ o0,
    const float* __restrict__ w1, unsigned short* __restrict__ o1,
    const float* __restrict__ w2, unsigned short* __restrict__ o2,
    const float* __restrict__ w3, unsigned short* __restrict__ o3)
{
    __shared__ float tile[32][33];
    const int bid = blockIdx.x;
    const float* in; unsigned short* out; int K, N, t;
    if (bid < 1728)      { in = w0; out = o0; K = 768;  N = 2304; t = bid; }
    else if (bid < 2304) { in = w1; out = o1; K = 768;  N = 768;  t = bid - 1728; }
    else if (bid < 4608) { in = w2; out = o2; K = 768;  N = 3072; t = bid - 2304; }
    else                 { in = w3; out = o3; K = 3072; N = 768;  t = bid - 4608; }
    const int nx = N / 32;
    const int n0 = (t % nx) * 32, k0 = (t / nx) * 32;
    const int tx = threadIdx.x, ty = threadIdx.y;   // block (32,8)
#pragma unroll
    for (int i = 0; i < 4; ++i)
        tile[ty + i * 8][tx] = in[(size_t)(k0 + ty + i * 8) * N + n0 + tx];
    __syncthreads();
#pragma unroll
    for (int i = 0; i < 4; ++i)
        out[(size_t)(n0 + ty + i * 8) * K + k0 + tx] = f2bf(tile[tx][ty + i * 8]);
}

// --------------------------------- layernorm -------------------------------
__global__ __launch_bounds__(256) void ln_fwd(
    const float* __restrict__ x, const float* __restrict__ w,
    unsigned short* __restrict__ out)
{
    const int row = blockIdx.x;
    const int tid = threadIdx.x;
    const size_t base = (size_t)row * DIM;
    float v0 = x[base + tid], v1 = x[base + tid + 256], v2 = x[base + tid + 512];
    float sum = v0 + v1 + v2;
    float sq  = v0 * v0 + v1 * v1 + v2 * v2;
#pragma unroll
    for (int off = 1; off < 64; off <<= 1) {
        sum += __shfl_xor(sum, off);
        sq  += __shfl_xor(sq,  off);
    }
    __shared__ float rs[4], rq[4];
    const int wid = tid >> 6, lane = tid & 63;
    if (lane == 0) { rs[wid] = sum; rq[wid] = sq; }
    __syncthreads();
    sum = rs[0] + rs[1] + rs[2] + rs[3];
    sq  = rq[0] + rq[1] + rq[2] + rq[3];
    const float mu   = sum * (1.0f / DIM);
    const float var  = sq * (1.0f / DIM) - mu * mu;
    const float rstd = rsqrtf(var + 1e-6f);
    out[base + tid]       = f2bf((v0 - mu) * rstd * w[tid]);
    out[base + tid + 256] = f2bf((v1 - mu) * rstd * w[tid + 256]);
    out[base + tid + 512] = f2bf((v2 - mu) * rstd * w[tid + 512]);
}

// ----------------------------------- GEMM ----------------------------------
// C[M][N] = A[M][K](bf16) x BT[N][K](bf16)^T.
// 3-stage LDS rotation, raw s_barrier + counted vmcnt (never 0 mid-loop):
//   iter k: waitcnt vmcnt(NVM) [stage(k) landed: in-order completion, and
//           stage(k+1) is the NVM youngest]; s_barrier; stage(k+2);
//           ds_read(k); MFMA(k).
// stage(k+2) is issued AFTER barrier(k) so it cannot race reads(k-1) of the
// same buffer ((k+2) == (k-1) mod 3).
// EPI 1: outf = res + C.  EPI 2: outb = bf16(gelu(C)).
// EPI 3 (QKV): q/k cols -> outb (qkv layout); v cols -> vt[b][h][d][L].
template<int EPI, int BM, int BN>
__global__ __launch_bounds__(256) void gemm_pipe(
    const unsigned short* __restrict__ A,
    const unsigned short* __restrict__ BT,
    const float* __restrict__ res,
    unsigned short* __restrict__ outb,
    float* __restrict__ outf,
    unsigned short* __restrict__ vt,
    int M, int N, int K)
{
    constexpr int WM = BM / 2, WN = BN / 2;
    constexpr int MI = WM / 16, NJ = WN / 16;
    constexpr int NVM = BM / 64 + BN / 64;     // gll per thread per stage
    __shared__ __align__(16) unsigned short As[3][BM * 32];
    __shared__ __align__(16) unsigned short Bs[3][BN * 32];
    const int tid = threadIdx.x, wid = tid >> 6;
    const int lane = tid & 63, l15 = lane & 15, g = lane >> 4;
    const int bm = blockIdx.x * BM, bn = blockIdx.y * BN;
    const int wm = (wid >> 1) * WM, wn = (wid & 1) * WN;

    const int srow = tid >> 2, scol = (tid & 3) * 8;
    const unsigned short* ag = A  + (size_t)(bm + srow) * K + scol;
    const unsigned short* bg = BT + (size_t)(bn + srow) * K + scol;

    auto stage = [&](int buf, int k0) {
#pragma unroll
        for (int s = 0; s < BM / 64; ++s)
            gll16(ag + (size_t)(s * 64) * K + k0, &As[buf][wid * 16 * 32 + s * 64 * 32]);
#pragma unroll
        for (int s = 0; s < BN / 64; ++s)
            gll16(bg + (size_t)(s * 64) * K + k0, &Bs[buf][wid * 16 * 32 + s * 64 * 32]);
    };

    const int NS = K / 32;
    f32x4 acc[MI][NJ] = {};
    stage(0, 0);
    stage(1, 32);
    int cur = 0;
    for (int ks = 0; ks < NS; ++ks) {
        if (ks + 1 < NS) {
            if constexpr (NVM == 4) asm volatile("s_waitcnt vmcnt(4)" ::: "memory");
            else                    asm volatile("s_waitcnt vmcnt(2)" ::: "memory");
        } else {
            asm volatile("s_waitcnt vmcnt(0)" ::: "memory");
        }
        __builtin_amdgcn_s_barrier();
        __builtin_amdgcn_sched_barrier(0);
        if (ks + 2 < NS) {
            const int nb = (cur + 2 >= 3) ? cur - 1 : cur + 2;
            stage(nb, (ks + 2) * 32);
        }
        bf16x8 af[MI], bfr[NJ];
#pragma unroll
        for (int i = 0; i < MI; ++i)
            af[i] = *(const bf16x8*)&As[cur][(wm + i * 16 + l15) * 32 + g * 8];
#pragma unroll
        for (int j = 0; j < NJ; ++j)
            bfr[j] = *(const bf16x8*)&Bs[cur][(wn + j * 16 + l15) * 32 + g * 8];
#pragma unroll
        for (int i = 0; i < MI; ++i)
#pragma unroll
            for (int j = 0; j < NJ; ++j)
                acc[i][j] = __builtin_amdgcn_mfma_f32_16x16x32_bf16(
                    af[i], bfr[j], acc[i][j], 0, 0, 0);
        cur = (cur + 1 >= 3) ? 0 : cur + 1;
    }
#pragma unroll
    for (int i = 0; i < MI; ++i)
#pragma unroll
        for (int j = 0; j < NJ; ++j) {
            const int row0 = bm + wm + i * 16 + g * 4;
            const int col  = bn + wn + j * 16 + l15;
            if (EPI == 3) {
                const int col0 = bn + wn + j * 16;     // wave-uniform
                const int rem0 = col0 % 192;
                if (rem0 < 128) {                      // q or k -> qkv layout
#pragma unroll
                    for (int r = 0; r < 4; ++r)
                        outb[(size_t)(row0 + r) * N + col] = f2bf(acc[i][j][r]);
                } else {                               // v -> vT[b][h][d][L]
                    const int hh = col0 / 192;
                    const int d  = rem0 - 128 + l15;
                    const int bb = row0 >> 11, ls = row0 & 2047;
                    ushort4v pv4;
#pragma unroll
                    for (int r = 0; r < 4; ++r) pv4[r] = f2bf(acc[i][j][r]);
                    *(ushort4v*)&vt[(((size_t)bb * NHEAD + hh) * HD + d) * SEQ + ls] = pv4;
                }
            } else {
#pragma unroll
                for (int r = 0; r < 4; ++r) {
                    const size_t idx = (size_t)(row0 + r) * N + col;
                    const float v = acc[i][j][r];
                    if (EPI == 1) {
                        outf[idx] = res[idx] + v;
                    } else if (EPI == 2) {
                        outb[idx] = f2bf(0.5f * v * (1.0f + erff(v * 0.70710678118654752f)));
                    } else {
                        outb[idx] = f2bf(v);
                    }
                }
            }
        }
}

// ------------------------------ MFMA flash attention -----------------------
// K from qkv (row-major), V from vT[b][h][d][L] (already transposed).
// Block = 256 thr (4 waves), one (b,h), 64 q rows (16/wave). KV tiles of 64.
// Reg-prefetch double-buffer, ONE barrier per tile.
// Swapped QK^T: S^T = mfma(A=K_tile, B=Q^T) so softmax col = q = lane&15.
__global__ __launch_bounds__(256) void attn_mfma(
    const unsigned short* __restrict__ qkv,
    const unsigned short* __restrict__ vT,
    unsigned short* __restrict__ o)
{
    __shared__ unsigned short Ks[2][64][72];     // [buf][kv][d]
    __shared__ unsigned short Vs[2][64][72];     // [buf][d][kv]  (V^T tile)
    __shared__ unsigned short Ps[4][16][72];     // per-wave [q][kv]
    const int tid = threadIdx.x, wid = tid >> 6, lane = tid & 63;
    const int l15 = lane & 15, g = lane >> 4;
    const int qt = blockIdx.x, bh = blockIdx.y;
    const int b = bh / NHEAD, h = bh % NHEAD;
    const size_t rowbase = (size_t)b * SEQ;

    // Q B-fragments straight from global: q = l15, d = g*8 + j (+32)
    const int qrow = qt * 64 + wid * 16 + l15;
    bf16x8 qf0, qf1;
    {
        const unsigned short* qp = qkv + (rowbase + qrow) * QKVW + h * 192 + g * 8;
        qf0 = *(const bf16x8*)qp;
        qf1 = *(const bf16x8*)(qp + 32);
    }

    // staging: thread covers rows srow, srow+32 (chunk sc..sc+7) of each tile
    const int srow = tid >> 3, sc = (tid & 7) * 8;
    const unsigned short* kg = qkv + (rowbase + srow) * QKVW + h * 192 + 64 + sc;
    const unsigned short* vg = vT + ((size_t)bh * HD + srow) * SEQ + sc;
    const size_t kstep = (size_t)64 * QKVW;

    float m_r = -1e30f, l_r = 0.f;
    f32x4 oacc[4] = {};                          // [dt]: d = dt*16+l15, q = g*4+r

    // prologue: stage tile 0 into buf 0
    ushort8 ka0 = *(const ushort8*)(kg);
    ushort8 ka1 = *(const ushort8*)(kg + 32 * QKVW);
    ushort8 va0 = *(const ushort8*)(vg);
    ushort8 va1 = *(const ushort8*)(vg + 32 * SEQ);
    *(ushort8*)&Ks[0][srow][sc]      = ka0;
    *(ushort8*)&Ks[0][srow + 32][sc] = ka1;
    *(ushort8*)&Vs[0][srow][sc]      = va0;
    *(ushort8*)&Vs[0][srow + 32][sc] = va1;
    __syncthreads();
    int cur = 0;

    for (int kt = 0; kt < SEQ / 64; ++kt) {
        const bool pf = (kt + 1 < SEQ / 64);
        if (pf) {                                // issue next tile's loads early
            const unsigned short* kp = kg + (size_t)(kt + 1) * kstep;
            const unsigned short* vp = vg + (kt + 1) * 64;
            ka0 = *(const ushort8*)(kp);
            ka1 = *(const ushort8*)(kp + 32 * QKVW);
            va0 = *(const ushort8*)(vp);
            va1 = *(const ushort8*)(vp + 32 * SEQ);
        }

        // S^T tiles: kv_local = st*16 + g*4 + r, q = l15
        f32x4 sc4[4];
#pragma unroll
        for (int st = 0; st < 4; ++st) {
            bf16x8 k0 = *(const bf16x8*)&Ks[cur][st * 16 + l15][g * 8];
            bf16x8 k1 = *(const bf16x8*)&Ks[cur][st * 16 + l15][32 + g * 8];
            f32x4 acc = {};
            acc = __builtin_amdgcn_mfma_f32_16x16x32_bf16(k0, qf0, acc, 0, 0, 0);
            acc = __builtin_amdgcn_mfma_f32_16x16x32_bf16(k1, qf1, acc, 0, 0, 0);
            sc4[st] = acc * ATT_SCALE;
        }

        // online softmax for q = l15 (stats replicated across the 4 g-groups)
        float tmax = -1e30f;
#pragma unroll
        for (int st = 0; st < 4; ++st)
#pragma unroll
            for (int r = 0; r < 4; ++r) tmax = fmaxf(tmax, sc4[st][r]);
        tmax = fmaxf(tmax, __shfl_xor(tmax, 16));
        tmax = fmaxf(tmax, __shfl_xor(tmax, 32));
        const float mn   = fmaxf(m_r, tmax);
        const float corr = __expf(m_r - mn);
        m_r = mn;
        float rsum = 0.f;
#pragma unroll
        for (int st = 0; st < 4; ++st) {
            const float p0 = __expf(sc4[st][0] - mn);
            const float p1 = __expf(sc4[st][1] - mn);
            const float p2 = __expf(sc4[st][2] - mn);
            const float p3 = __expf(sc4[st][3] - mn);
            rsum += (p0 + p1) + (p2 + p3);
            u32x2 w;
            w[0] = cvt_pk_bf16(p0, p1);
            w[1] = cvt_pk_bf16(p2, p3);
            *(u32x2*)&Ps[wid][l15][st * 16 + g * 4] = w;   // P[q][kv]
        }
        rsum += __shfl_xor(rsum, 16);
        rsum += __shfl_xor(rsum, 32);
        l_r = l_r * corr + rsum;

        // rescale O (its q = g*4+r; corr lives at lane q for q<16)
#pragma unroll
        for (int r = 0; r < 4; ++r) {
            const float c = __shfl(corr, g * 4 + r);
#pragma unroll
            for (int dt = 0; dt < 4; ++dt) oacc[dt][r] *= c;
        }

        // PV: O[q][d] += P[q][kv] V[kv][d]; V^T rows read as b128
#pragma unroll
        for (int kk = 0; kk < 2; ++kk) {
            bf16x8 pfr = *(const bf16x8*)&Ps[wid][l15][kk * 32 + g * 8];
#pragma unroll
            for (int dt = 0; dt < 4; ++dt) {
                bf16x8 vf = *(const bf16x8*)&Vs[cur][dt * 16 + l15][kk * 32 + g * 8];
                oacc[dt] = __builtin_amdgcn_mfma_f32_16x16x32_bf16(pfr, vf, oacc[dt], 0, 0, 0);
            }
        }

        if (pf) {                                // write next tile to other buf
            *(ushort8*)&Ks[cur ^ 1][srow][sc]      = ka0;
            *(ushort8*)&Ks[cur ^ 1][srow + 32][sc] = ka1;
            *(ushort8*)&Vs[cur ^ 1][srow][sc]      = va0;
            *(ushort8*)&Vs[cur ^ 1][srow + 32][sc] = va1;
        }
        __syncthreads();                         // one barrier per tile
        cur ^= 1;
    }

#pragma unroll
    for (int r = 0; r < 4; ++r) {
        const float li  = __shfl(l_r, g * 4 + r);
        const float inv = 1.0f / li;
        const int   row = qt * 64 + wid * 16 + g * 4 + r;
#pragma unroll
        for (int dt = 0; dt < 4; ++dt)
            o[(rowbase + row) * DIM + h * HD + dt * 16 + l15] = f2bf(oacc[dt][r] * inv);
    }
}

// -------------------------------- launcher ---------------------------------
extern "C" void kernel_launch(void* const* d_in, const int* in_sizes, int n_in,
                              void* d_out, int out_size, void* d_ws, size_t ws_size,
                              hipStream_t stream)
{
    const float* x     = (const float*)d_in[0];
    const float* ln1w  = (const float*)d_in[2];
    const float* ln2w  = (const float*)d_in[3];
    const float* wqkv  = (const float*)d_in[4];
    const float* wproj = (const float*)d_in[5];
    const float* wmlp1 = (const float*)d_in[6];
    const float* wmlp2 = (const float*)d_in[7];
    float* out = (float*)d_out;

    char* ws = (char*)d_ws;
    size_t off = 0;
    auto alloc = [&](size_t nbytes) -> void* {
        void* p = (void*)(ws + off);
        off += (nbytes + 255) & ~(size_t)255;
        return p;
    };
    unsigned short* hb     = (unsigned short*)alloc((size_t)ROWS * DIM  * 2);
    unsigned short* qkvb   = (unsigned short*)alloc((size_t)ROWS * QKVW * 2);
    unsigned short* vt     = (unsigned short*)alloc((size_t)BATCH * NHEAD * HD * SEQ * 2);
    unsigned short* ob     = (unsigned short*)alloc((size_t)ROWS * DIM  * 2);
    float*          x1     = (float*)         alloc((size_t)ROWS * DIM  * 4);
    unsigned short* h2b    = (unsigned short*)alloc((size_t)ROWS * DIM  * 2);
    unsigned short* gb     = (unsigned short*)alloc((size_t)ROWS * MLPH * 2);
    unsigned short* wqkvT  = (unsigned short*)alloc((size_t)QKVW * DIM * 2);
    unsigned short* wprojT = (unsigned short*)alloc((size_t)DIM  * DIM * 2);
    unsigned short* wmlp1T = (unsigned short*)alloc((size_t)MLPH * DIM * 2);
    unsigned short* wmlp2T = (unsigned short*)alloc((size_t)DIM  * MLPH * 2);

    transpose_cast_all<<<6912, dim3(32, 8), 0, stream>>>(
        wqkv, wqkvT, wproj, wprojT, wmlp1, wmlp1T, wmlp2, wmlp2T);

    ln_fwd<<<ROWS, 256, 0, stream>>>(x, ln1w, hb);

    gemm_pipe<3, 128, 128><<<dim3(ROWS / 128, QKVW / 128), 256, 0, stream>>>(
        hb, wqkvT, nullptr, qkvb, nullptr, vt, ROWS, QKVW, DIM);

    attn_mfma<<<dim3(SEQ / 64, BATCH * NHEAD), 256, 0, stream>>>(qkvb, vt, ob);

    gemm_pipe<1, 64, 64><<<dim3(ROWS / 64, DIM / 64), 256, 0, stream>>>(
        ob, wprojT, x, nullptr, x1, nullptr, ROWS, DIM, DIM);

    ln_fwd<<<ROWS, 256, 0, stream>>>(x1, ln2w, h2b);

    gemm_pipe<2, 128, 128><<<dim3(ROWS / 128, MLPH / 128), 256, 0, stream>>>(
        h2b, wmlp1T, nullptr, gb, nullptr, nullptr, ROWS, MLPH, DIM);

    gemm_pipe<1, 64, 64><<<dim3(ROWS / 64, DIM / 64), 256, 0, stream>>>(
        gb, wmlp2T, x1, nullptr, out, nullptr, ROWS, DIM, MLPH);
}